// Round 1
// baseline (114.576 us; speedup 1.0000x reference)
//
#include <hip/hip_runtime.h>
#include <math.h>

// Problem constants (from reference setup_inputs)
#define B 64
#define S 2048
#define H 1024
#define SPLIT 16
#define ROWS_PER_BLOCK (S / SPLIT)              // 128
#define THREADS 256
#define WAVES 4
#define ROWS_PER_WAVE (ROWS_PER_BLOCK / WAVES)  // 32

// ---------------------------------------------------------------------------
// Pass 1: fused score + online-softmax context accumulation.
// One block handles one (b, split) chunk of 128 sequence rows.
// Each wave (64 lanes) processes whole rows: lane l holds dec/ctx elements
// h = c*256 + l*4 + j  (c=0..3, j=0..3)  -> 16 floats/lane = full H=1024.
// ---------------------------------------------------------------------------
__global__ __launch_bounds__(THREADS)
void luong_pass1(const float* __restrict__ dec_h,
                 const float* __restrict__ dec_c,
                 const float* __restrict__ enc,
                 float* __restrict__ attn_raw,   // d_out + B*H, raw scores
                 float* __restrict__ ctx_part,   // [B][SPLIT][H]
                 float* __restrict__ mz_part) {  // [B][SPLIT][2]
  const int bid  = blockIdx.x;
  const int b    = bid / SPLIT;
  const int sp   = bid % SPLIT;
  const int t    = threadIdx.x;
  const int w    = t >> 6;     // wave id 0..3
  const int lane = t & 63;

  // dec = dec_h + dec_c, distributed 16 elems per lane (same for all waves)
  float4 dec[4];
  const float4* dh = (const float4*)(dec_h + (size_t)b * H);
  const float4* dc = (const float4*)(dec_c + (size_t)b * H);
#pragma unroll
  for (int c = 0; c < 4; ++c) {
    float4 a  = dh[c * 64 + lane];
    float4 bb = dc[c * 64 + lane];
    dec[c] = make_float4(a.x + bb.x, a.y + bb.y, a.z + bb.z, a.w + bb.w);
  }

  float m = -INFINITY;
  float Z = 0.f;
  float ctx[16];
#pragma unroll
  for (int k = 0; k < 16; ++k) ctx[k] = 0.f;

  const int s_base = sp * ROWS_PER_BLOCK + w;
  for (int r = 0; r < ROWS_PER_WAVE; ++r) {
    const int s = s_base + r * WAVES;
    const float4* erow = (const float4*)(enc + ((size_t)b * S + s) * H);
    float4 e[4];
#pragma unroll
    for (int c = 0; c < 4; ++c) e[c] = erow[c * 64 + lane];

    // score = <enc_row, dec>
    float partial = 0.f;
#pragma unroll
    for (int c = 0; c < 4; ++c)
      partial += e[c].x * dec[c].x + e[c].y * dec[c].y +
                 e[c].z * dec[c].z + e[c].w * dec[c].w;
#pragma unroll
    for (int off = 32; off >= 1; off >>= 1)
      partial += __shfl_xor(partial, off, 64);
    const float score = partial;  // all 64 lanes hold it

    if (lane == 0) attn_raw[b * S + s] = score;  // raw score; fixed up later

    // online softmax update (wave-uniform branch)
    if (score > m) {
      const float f = expf(m - score);
      Z *= f;
#pragma unroll
      for (int k = 0; k < 16; ++k) ctx[k] *= f;
      m = score;
    }
    const float p = expf(score - m);
    Z += p;
#pragma unroll
    for (int c = 0; c < 4; ++c) {
      ctx[c * 4 + 0] += p * e[c].x;
      ctx[c * 4 + 1] += p * e[c].y;
      ctx[c * 4 + 2] += p * e[c].z;
      ctx[c * 4 + 3] += p * e[c].w;
    }
  }

  // ---- combine the 4 waves of this block via LDS ----
  __shared__ float ctx_lds[WAVES][H];  // 16 KiB
  __shared__ float mzs[WAVES][2];
#pragma unroll
  for (int c = 0; c < 4; ++c) {
    float4 v = make_float4(ctx[c * 4 + 0], ctx[c * 4 + 1],
                           ctx[c * 4 + 2], ctx[c * 4 + 3]);
    ((float4*)&ctx_lds[w][c * 256])[lane] = v;
  }
  if (lane == 0) { mzs[w][0] = m; mzs[w][1] = Z; }
  __syncthreads();

  const float M = fmaxf(fmaxf(mzs[0][0], mzs[1][0]),
                        fmaxf(mzs[2][0], mzs[3][0]));
  float fac[WAVES];
  float Zb = 0.f;
#pragma unroll
  for (int i = 0; i < WAVES; ++i) {
    fac[i] = expf(mzs[i][0] - M);
    Zb += mzs[i][1] * fac[i];
  }

  float* outp = ctx_part + ((size_t)b * SPLIT + sp) * H;
#pragma unroll
  for (int q = 0; q < 4; ++q) {
    const int h = q * 256 + t;
    float v = 0.f;
#pragma unroll
    for (int i = 0; i < WAVES; ++i) v += ctx_lds[i][h] * fac[i];
    outp[h] = v;
  }
  if (t == 0) {
    mz_part[(b * SPLIT + sp) * 2 + 0] = M;
    mz_part[(b * SPLIT + sp) * 2 + 1] = Zb;
  }
}

// ---------------------------------------------------------------------------
// Pass 2: merge the SPLIT partials per batch -> context vector + final (M, Z)
// ---------------------------------------------------------------------------
__global__ __launch_bounds__(256)
void luong_combine(const float* __restrict__ ctx_part,
                   const float* __restrict__ mz_part,
                   float* __restrict__ ctx_out,    // d_out
                   float* __restrict__ mz_final) { // [B][2]
  const int b = blockIdx.x;
  const int t = threadIdx.x;

  float m_i[SPLIT], z_i[SPLIT];
  float M = -INFINITY;
#pragma unroll
  for (int i = 0; i < SPLIT; ++i) {
    m_i[i] = mz_part[(b * SPLIT + i) * 2 + 0];
    z_i[i] = mz_part[(b * SPLIT + i) * 2 + 1];
    M = fmaxf(M, m_i[i]);
  }
  float fac[SPLIT];
  float Z = 0.f;
#pragma unroll
  for (int i = 0; i < SPLIT; ++i) {
    fac[i] = expf(m_i[i] - M);
    Z += z_i[i] * fac[i];
  }
  const float invZ = 1.f / Z;

#pragma unroll
  for (int q = 0; q < 4; ++q) {
    const int h = q * 256 + t;
    float v = 0.f;
#pragma unroll
    for (int i = 0; i < SPLIT; ++i)
      v += ctx_part[((size_t)(b * SPLIT + i)) * H + h] * fac[i];
    ctx_out[(size_t)b * H + h] = v * invZ;
  }
  if (t == 0) {
    mz_final[2 * b + 0] = M;
    mz_final[2 * b + 1] = Z;
  }
}

// ---------------------------------------------------------------------------
// Pass 3: normalize raw scores in place -> softmax attention weights
// ---------------------------------------------------------------------------
__global__ __launch_bounds__(256)
void luong_fixup(float* __restrict__ attn,
                 const float* __restrict__ mz_final) {
  const int idx = blockIdx.x * blockDim.x + threadIdx.x;
  if (idx >= B * S) return;
  const int b = idx >> 11;  // S = 2048
  const float M = mz_final[2 * b + 0];
  const float Z = mz_final[2 * b + 1];
  attn[idx] = expf(attn[idx] - M) / Z;
}

extern "C" void kernel_launch(void* const* d_in, const int* in_sizes, int n_in,
                              void* d_out, int out_size, void* d_ws, size_t ws_size,
                              hipStream_t stream) {
  const float* dec_h = (const float*)d_in[0];
  const float* dec_c = (const float*)d_in[1];
  const float* enc   = (const float*)d_in[2];

  float* ctx_out = (float*)d_out;            // [B][H]
  float* attn    = (float*)d_out + B * H;    // [B][S]

  float* ctx_part = (float*)d_ws;                             // B*SPLIT*H floats = 4 MiB
  float* mz_part  = ctx_part + (size_t)B * SPLIT * H;         // B*SPLIT*2
  float* mz_final = mz_part + (size_t)B * SPLIT * 2;          // B*2

  luong_pass1<<<B * SPLIT, THREADS, 0, stream>>>(dec_h, dec_c, enc, attn,
                                                 ctx_part, mz_part);
  luong_combine<<<B, 256, 0, stream>>>(ctx_part, mz_part, ctx_out, mz_final);
  luong_fixup<<<(B * S + 255) / 256, 256, 0, stream>>>(attn, mz_final);
}